// Round 2
// baseline (912.814 us; speedup 1.0000x reference)
//
#include <hip/hip_runtime.h>
#include <math.h>

// ---------------------------------------------------------------------------
// GAT decoder: 3 layers, N=50000 nodes, E=800000 edges, fp32.
// Pipeline per launch:
//   CSR build (histogram -> scan -> scatter), reused by all 3 layers
//   per layer: GEMM h=x@W ; scores a_s/a_d ; per-dst ONLINE softmax (m, 1/den)
//              ; wave-per-node aggregation, alpha recomputed inline,
//                float4 gathers of h[src]
// ---------------------------------------------------------------------------

#define SLOPE 0.2f

__device__ __forceinline__ int wave_incl_scan(int v) {
#pragma unroll
  for (int off = 1; off < 64; off <<= 1) {
    int t = __shfl_up(v, off, 64);
    if ((int)(threadIdx.x & 63) >= off) v += t;
  }
  return v;
}

// ---- CSR build ------------------------------------------------------------

__global__ void k_hist(const int* __restrict__ dst, int E, int* __restrict__ rowptr) {
  int e = blockIdx.x * blockDim.x + threadIdx.x;
  if (e < E) atomicAdd(&rowptr[dst[e] + 1], 1);
}

// inclusive scan of data[0..n) in chunks of 1024; block b writes its total to sums[b]
__global__ __launch_bounds__(1024) void k_scan_block(int* __restrict__ data, int n,
                                                     int* __restrict__ sums) {
  int tid = threadIdx.x;
  int gid = blockIdx.x * 1024 + tid;
  int v = (gid < n) ? data[gid] : 0;
  int sv = wave_incl_scan(v);
  __shared__ int wsum[16];
  int w = tid >> 6, l = tid & 63;
  if (l == 63) wsum[w] = sv;
  __syncthreads();
  if (w == 0) {
    int x = (l < 16) ? wsum[l] : 0;
    x = wave_incl_scan(x);
    if (l < 16) wsum[l] = x;
  }
  __syncthreads();
  if (w > 0) sv += wsum[w - 1];
  if (gid < n) data[gid] = sv;
  if (tid == 1023 && sums) sums[blockIdx.x] = sv;
}

__global__ void k_scan_add(int* __restrict__ data, int n, const int* __restrict__ sums) {
  int gid = blockIdx.x * blockDim.x + threadIdx.x;
  if (gid < n) {
    int b = gid >> 10;
    if (b > 0) data[gid] += sums[b - 1];
  }
}

__global__ void k_copy_i32(const int* __restrict__ a, int* __restrict__ b, int n) {
  int i = blockIdx.x * blockDim.x + threadIdx.x;
  if (i < n) b[i] = a[i];
}

__global__ void k_scatter(const int* __restrict__ src, const int* __restrict__ dst, int E,
                          int* __restrict__ rowcur, int* __restrict__ permsrc) {
  int e = blockIdx.x * blockDim.x + threadIdx.x;
  if (e < E) {
    int d = dst[e];
    int pos = atomicAdd(&rowcur[d], 1);
    permsrc[pos] = src[e];
  }
}

// ---- GEMM: C[M,NC] = A[M,K] @ B[K,NC], BM=BN=64, BK=16, 256 thr, 4x4/thr ---

__global__ __launch_bounds__(256) void k_gemm64(const float* __restrict__ A,
                                                const float* __restrict__ B,
                                                float* __restrict__ C,
                                                int M, int K, int NC) {
  __shared__ float As[16][68];  // [k][m], padded row
  __shared__ float Bs[16][64];  // [k][n]
  int tid = threadIdx.x;
  int tx = tid & 15, ty = tid >> 4;
  int bm = blockIdx.x * 64, bn = blockIdx.y * 64;
  int ar = tid >> 2;          // 0..63 (row within tile)
  int ak = (tid & 3) << 2;    // 0,4,8,12
  int bk = tid >> 4;          // 0..15
  int bn4 = (tid & 15) << 2;  // 0..60
  const bool arow_ok = (bm + ar) < M;
  float acc[4][4] = {};
  for (int k0 = 0; k0 < K; k0 += 16) {
    float4 av = make_float4(0.f, 0.f, 0.f, 0.f);
    if (arow_ok) av = *(const float4*)(A + (size_t)(bm + ar) * K + k0 + ak);
    float4 bv = *(const float4*)(B + (size_t)(k0 + bk) * NC + bn + bn4);
    As[ak + 0][ar] = av.x;
    As[ak + 1][ar] = av.y;
    As[ak + 2][ar] = av.z;
    As[ak + 3][ar] = av.w;
    *(float4*)&Bs[bk][bn4] = bv;
    __syncthreads();
#pragma unroll
    for (int k = 0; k < 16; ++k) {
      float4 a = *(const float4*)&As[k][ty << 2];
      float4 b = *(const float4*)&Bs[k][tx << 2];
      acc[0][0] += a.x * b.x; acc[0][1] += a.x * b.y; acc[0][2] += a.x * b.z; acc[0][3] += a.x * b.w;
      acc[1][0] += a.y * b.x; acc[1][1] += a.y * b.y; acc[1][2] += a.y * b.z; acc[1][3] += a.y * b.w;
      acc[2][0] += a.z * b.x; acc[2][1] += a.z * b.y; acc[2][2] += a.z * b.z; acc[2][3] += a.z * b.w;
      acc[3][0] += a.w * b.x; acc[3][1] += a.w * b.y; acc[3][2] += a.w * b.z; acc[3][3] += a.w * b.w;
    }
    __syncthreads();
  }
#pragma unroll
  for (int i = 0; i < 4; ++i) {
    int row = bm + (ty << 2) + i;
    if (row < M) {
      float4 o = make_float4(acc[i][0], acc[i][1], acc[i][2], acc[i][3]);
      *(float4*)(C + (size_t)row * NC + bn + (tx << 2)) = o;
    }
  }
}

// ---- attention scores: a_s[n,h] = <h[n,h,:], att_src[h,:]>, same for dst ---

template <int H, int C>
__global__ void k_scores(const float* __restrict__ h, const float* __restrict__ att_s,
                         const float* __restrict__ att_d, float* __restrict__ a_s,
                         float* __restrict__ a_d, int Nn) {
  int t = blockIdx.x * blockDim.x + threadIdx.x;
  if (t >= Nn * H) return;
  int n = t / H, hh = t % H;
  const float4* hp = (const float4*)(h + (size_t)n * (H * C) + hh * C);
  const float4* sp = (const float4*)(att_s + hh * C);
  const float4* dp = (const float4*)(att_d + hh * C);
  float s = 0.f, d = 0.f;
#pragma unroll
  for (int c = 0; c < C / 4; ++c) {
    float4 v = hp[c], a = sp[c], b = dp[c];
    s += v.x * a.x + v.y * a.y + v.z * a.z + v.w * a.w;
    d += v.x * b.x + v.y * b.y + v.z * b.z + v.w * b.w;
  }
  a_s[t] = s;
  a_d[t] = d;
}

// ---- per-dst ONLINE segment softmax over CSR (thread per node) -------------
// outputs: m_out[n,h] (finite running max, 0 if no edges), inv_den[n,h]

template <int H>
__global__ void k_softmax(const int* __restrict__ rowptr, const int* __restrict__ permsrc,
                          const float* __restrict__ a_s, const float* __restrict__ a_d,
                          float* __restrict__ m_out, float* __restrict__ inv_den, int Nn) {
  int n = blockIdx.x * blockDim.x + threadIdx.x;
  if (n >= Nn) return;
  int start = rowptr[n], end = rowptr[n + 1];
  float ad[H], m[H], den[H];
  if constexpr (H == 4) {
    float4 v = ((const float4*)a_d)[n];
    ad[0] = v.x; ad[1] = v.y; ad[2] = v.z; ad[3] = v.w;
  } else {
    ad[0] = a_d[n];
  }
#pragma unroll
  for (int h = 0; h < H; ++h) {
    m[h] = -INFINITY;
    den[h] = 0.f;
  }
  for (int p = start; p < end; ++p) {
    int s = permsrc[p];
    float as[H];
    if constexpr (H == 4) {
      float4 v = ((const float4*)a_s)[s];
      as[0] = v.x; as[1] = v.y; as[2] = v.z; as[3] = v.w;
    } else {
      as[0] = a_s[s];
    }
#pragma unroll
    for (int h = 0; h < H; ++h) {
      float e = as[h] + ad[h];
      e = e > 0.f ? e : SLOPE * e;
      float mn = fmaxf(m[h], e);
      den[h] = den[h] * expf(m[h] - mn) + expf(e - mn);
      m[h] = mn;
    }
  }
#pragma unroll
  for (int h = 0; h < H; ++h) {
    m_out[(size_t)n * H + h] = isfinite(m[h]) ? m[h] : 0.f;
    inv_den[(size_t)n * H + h] = 1.f / (den[h] + 1e-16f);
  }
}

// ---- aggregation: wave per node, lanes split HC cols, float4 gathers -------
// alpha recomputed inline: alpha = exp(leaky(a_s[s]+a_d[n]) - m[n]) * inv_den[n]

template <int H, int C>
__global__ void k_aggregate(const int* __restrict__ rowptr, const int* __restrict__ permsrc,
                            const float* __restrict__ a_s, const float* __restrict__ a_d,
                            const float* __restrict__ m_arr, const float* __restrict__ inv_den,
                            const float* __restrict__ h, const float* __restrict__ bias,
                            float* __restrict__ out, int Nn) {
  constexpr int HC = H * C;
  constexpr int PL = HC / 64;  // floats per lane: 4 (HC=256) or 2 (HC=128)
  int gw = (blockIdx.x * blockDim.x + threadIdx.x) >> 6;
  if (gw >= Nn) return;
  int lane = threadIdx.x & 63;
  int col0 = lane * PL;
  int hh = col0 / C;
  int start = rowptr[gw], end = rowptr[gw + 1];
  float adv = a_d[(size_t)gw * H + hh];
  float mv = m_arr[(size_t)gw * H + hh];
  float idn = inv_den[(size_t)gw * H + hh];
  float acc[PL] = {};
  for (int c0 = start; c0 < end; c0 += 64) {
    int myp = c0 + lane;
    int sv = (myp < end) ? permsrc[myp] : 0;
    int cnt = min(64, end - c0);
    for (int j = 0; j < cnt; ++j) {
      int s = __shfl(sv, j, 64);
      float e = a_s[(size_t)s * H + hh] + adv;
      e = e > 0.f ? e : SLOPE * e;
      float alpha = expf(e - mv) * idn;
      const float* hp = h + (size_t)s * HC + col0;
      if constexpr (PL == 4) {
        float4 v = *(const float4*)hp;
        acc[0] += alpha * v.x;
        acc[1] += alpha * v.y;
        acc[2] += alpha * v.z;
        acc[3] += alpha * v.w;
      } else {
        float2 v = *(const float2*)hp;
        acc[0] += alpha * v.x;
        acc[1] += alpha * v.y;
      }
    }
  }
#pragma unroll
  for (int j = 0; j < PL; ++j)
    out[(size_t)gw * HC + col0 + j] = acc[j] + bias[col0 + j];
}

// ---------------------------------------------------------------------------

extern "C" void kernel_launch(void* const* d_in, const int* in_sizes, int n_in,
                              void* d_out, int out_size, void* d_ws, size_t ws_size,
                              hipStream_t stream) {
  const float* x = (const float*)d_in[0];
  const int* ei = (const int*)d_in[1];
  const int Nn = in_sizes[0] / 256;
  const int E = in_sizes[1] / 2;
  const int* srcI = ei;
  const int* dstI = ei + E;

  const float* W[3]   = {(const float*)d_in[3], (const float*)d_in[7],  (const float*)d_in[11]};
  const float* ats[3] = {(const float*)d_in[4], (const float*)d_in[8],  (const float*)d_in[12]};
  const float* atd[3] = {(const float*)d_in[5], (const float*)d_in[9],  (const float*)d_in[13]};
  const float* bia[3] = {(const float*)d_in[6], (const float*)d_in[10], (const float*)d_in[14]};

  // workspace carve-up (256B aligned). Total ~110 MB.
  char* p = (char*)d_ws;
  auto alloc = [&](size_t bytes) {
    void* r = (void*)p;
    p += (bytes + 255) & ~(size_t)255;
    return r;
  };
  int* rowptr = (int*)alloc((size_t)(Nn + 1) * sizeof(int));
  int* rowcur = (int*)alloc((size_t)Nn * sizeof(int));
  int* permsrc = (int*)alloc((size_t)E * sizeof(int));
  int* ssum = (int*)alloc(1024 * sizeof(int));
  float* hbuf = (float*)alloc((size_t)Nn * 256 * sizeof(float));
  float* buf0 = (float*)alloc((size_t)Nn * 256 * sizeof(float));
  float* a_s = (float*)alloc((size_t)Nn * 4 * sizeof(float));
  float* a_d = (float*)alloc((size_t)Nn * 4 * sizeof(float));
  float* m_arr = (float*)alloc((size_t)Nn * 4 * sizeof(float));
  float* idn = (float*)alloc((size_t)Nn * 4 * sizeof(float));

  // ---- CSR build (once; reused by all layers) ----
  hipMemsetAsync(rowptr, 0, (size_t)(Nn + 1) * sizeof(int), stream);
  const int TB = 256;
  k_hist<<<(E + TB - 1) / TB, TB, 0, stream>>>(dstI, E, rowptr);
  int n1 = Nn + 1;
  int nblk = (n1 + 1023) / 1024;
  k_scan_block<<<nblk, 1024, 0, stream>>>(rowptr, n1, ssum);
  k_scan_block<<<1, 1024, 0, stream>>>(ssum, nblk, (int*)nullptr);
  k_scan_add<<<(n1 + TB - 1) / TB, TB, 0, stream>>>(rowptr, n1, ssum);
  k_copy_i32<<<(Nn + TB - 1) / TB, TB, 0, stream>>>(rowptr, rowcur, Nn);
  k_scatter<<<(E + TB - 1) / TB, TB, 0, stream>>>(srcI, dstI, E, rowcur, permsrc);

  // ---- layers ----
  // Layer inputs/outputs: x -> buf0 -> buf0 -> d_out. (Layer1 writes back into
  // buf0: safe because the GEMM consumed it into hbuf before aggregation runs.)
  const float* xin = x;
  float* outs[3] = {buf0, buf0, (float*)d_out};
  for (int l = 0; l < 3; ++l) {
    const int H = (l == 2) ? 1 : 4;
    const int HC = (l == 2) ? 128 : 256;
    dim3 g((Nn + 63) / 64, HC / 64);
    k_gemm64<<<g, 256, 0, stream>>>(xin, W[l], hbuf, Nn, 256, HC);
    if (H == 4) {
      k_scores<4, 64><<<(Nn * 4 + TB - 1) / TB, TB, 0, stream>>>(hbuf, ats[l], atd[l], a_s, a_d, Nn);
      k_softmax<4><<<(Nn + TB - 1) / TB, TB, 0, stream>>>(rowptr, permsrc, a_s, a_d, m_arr, idn, Nn);
      k_aggregate<4, 64><<<(Nn + 3) / 4, 256, 0, stream>>>(rowptr, permsrc, a_s, a_d, m_arr, idn,
                                                           hbuf, bia[l], outs[l], Nn);
    } else {
      k_scores<1, 128><<<(Nn + TB - 1) / TB, TB, 0, stream>>>(hbuf, ats[l], atd[l], a_s, a_d, Nn);
      k_softmax<1><<<(Nn + TB - 1) / TB, TB, 0, stream>>>(rowptr, permsrc, a_s, a_d, m_arr, idn, Nn);
      k_aggregate<1, 128><<<(Nn + 3) / 4, 256, 0, stream>>>(rowptr, permsrc, a_s, a_d, m_arr, idn,
                                                            hbuf, bia[l], outs[l], Nn);
    }
    xin = outs[l];
  }
}

// Round 13
// 873.544 us; speedup vs baseline: 1.0450x; 1.0450x over previous
//
#include <hip/hip_runtime.h>
#include <math.h>

// ---------------------------------------------------------------------------
// GAT decoder: 3 layers, N=50000 nodes, E=800000 edges, fp32.
//   CSR build (histogram -> scan -> scatter), reused by all 3 layers
//   per layer: GEMM h=x@W (128x128 tile, 8x8 microtile) ; scores ; online
//              softmax (m, 1/den) ; wave-per-node aggregation with depth-2
//              prefetch of h[src] row gathers
// ---------------------------------------------------------------------------

#define SLOPE 0.2f

__device__ __forceinline__ int wave_incl_scan(int v) {
#pragma unroll
  for (int off = 1; off < 64; off <<= 1) {
    int t = __shfl_up(v, off, 64);
    if ((int)(threadIdx.x & 63) >= off) v += t;
  }
  return v;
}

// ---- CSR build ------------------------------------------------------------

__global__ void k_hist(const int* __restrict__ dst, int E, int* __restrict__ rowptr) {
  int e = blockIdx.x * blockDim.x + threadIdx.x;
  if (e < E) atomicAdd(&rowptr[dst[e] + 1], 1);
}

__global__ __launch_bounds__(1024) void k_scan_block(int* __restrict__ data, int n,
                                                     int* __restrict__ sums) {
  int tid = threadIdx.x;
  int gid = blockIdx.x * 1024 + tid;
  int v = (gid < n) ? data[gid] : 0;
  int sv = wave_incl_scan(v);
  __shared__ int wsum[16];
  int w = tid >> 6, l = tid & 63;
  if (l == 63) wsum[w] = sv;
  __syncthreads();
  if (w == 0) {
    int x = (l < 16) ? wsum[l] : 0;
    x = wave_incl_scan(x);
    if (l < 16) wsum[l] = x;
  }
  __syncthreads();
  if (w > 0) sv += wsum[w - 1];
  if (gid < n) data[gid] = sv;
  if (tid == 1023 && sums) sums[blockIdx.x] = sv;
}

// adds block-prefix sums; also seeds rowcur[i] = rowptr[i] for the scatter
__global__ void k_scan_add(int* __restrict__ data, int n, const int* __restrict__ sums,
                           int* __restrict__ rowcur, int nrow) {
  int gid = blockIdx.x * blockDim.x + threadIdx.x;
  if (gid < n) {
    int b = gid >> 10;
    int v = data[gid];
    if (b > 0) v += sums[b - 1];
    data[gid] = v;
    if (gid < nrow) rowcur[gid] = v;
  }
}

__global__ void k_scatter(const int* __restrict__ src, const int* __restrict__ dst, int E,
                          int* __restrict__ rowcur, int* __restrict__ permsrc) {
  int e = blockIdx.x * blockDim.x + threadIdx.x;
  if (e < E) {
    int d = dst[e];
    int pos = atomicAdd(&rowcur[d], 1);
    permsrc[pos] = src[e];
  }
}

// ---- GEMM: C[M,NC] = A[M,K] @ B[K,NC]; BM=BN=128, BK=16, 256 thr, 8x8 ------
// Bs columns are skewed (pc = c + (c>>5)*4) to break the 4-way bank conflict
// between colg = {0,32,64,96} within a row (2-way after skew = free).
// Row width MUST be >= 140: bskew(120)+7 = 139 (R5 bugfix: was 136, OOB).

__device__ __forceinline__ int bskew(int c) { return c + ((c >> 5) << 2); }

__global__ __launch_bounds__(256) void k_gemm128(const float* __restrict__ A,
                                                 const float* __restrict__ B,
                                                 float* __restrict__ C,
                                                 int M, int K, int NC) {
  __shared__ float As[16][132];
  __shared__ float Bs[16][140];
  int tid = threadIdx.x;
  int bm = blockIdx.x * 128, bn = blockIdx.y * 128;
  int ar = tid >> 1;            // 0..127  A row within tile
  int ac = (tid & 1) << 3;      // 0 or 8  A k-offset
  int br = tid >> 4;            // 0..15   B k-row
  int bc = (tid & 15) << 3;     // 0..120  B col
  int pbc = bskew(bc);
  int rowg = (tid >> 4) << 3;   // 0..120  micro-tile row base
  int colg = (tid & 15) << 3;   // 0..120  micro-tile col base
  int pcolg = bskew(colg);
  const bool aok = (bm + ar) < M;
  float acc[8][8] = {};
  for (int k0 = 0; k0 < K; k0 += 16) {
    float4 a0 = make_float4(0.f, 0.f, 0.f, 0.f), a1 = a0;
    if (aok) {
      const float* ap = A + (size_t)(bm + ar) * K + k0 + ac;
      a0 = *(const float4*)ap;
      a1 = *(const float4*)(ap + 4);
    }
    const float* bp = B + (size_t)(k0 + br) * NC + bn + bc;
    float4 b0 = *(const float4*)bp;
    float4 b1 = *(const float4*)(bp + 4);
    __syncthreads();  // previous inner loop done before overwrite
    As[ac + 0][ar] = a0.x; As[ac + 1][ar] = a0.y;
    As[ac + 2][ar] = a0.z; As[ac + 3][ar] = a0.w;
    As[ac + 4][ar] = a1.x; As[ac + 5][ar] = a1.y;
    As[ac + 6][ar] = a1.z; As[ac + 7][ar] = a1.w;
    *(float4*)&Bs[br][pbc] = b0;
    *(float4*)&Bs[br][pbc + 4] = b1;
    __syncthreads();
#pragma unroll
    for (int k = 0; k < 16; ++k) {
      float4 a0v = *(const float4*)&As[k][rowg];
      float4 a1v = *(const float4*)&As[k][rowg + 4];
      float4 b0v = *(const float4*)&Bs[k][pcolg];
      float4 b1v = *(const float4*)&Bs[k][pcolg + 4];
      float av[8] = {a0v.x, a0v.y, a0v.z, a0v.w, a1v.x, a1v.y, a1v.z, a1v.w};
      float bv[8] = {b0v.x, b0v.y, b0v.z, b0v.w, b1v.x, b1v.y, b1v.z, b1v.w};
#pragma unroll
      for (int i = 0; i < 8; ++i)
#pragma unroll
        for (int j = 0; j < 8; ++j) acc[i][j] += av[i] * bv[j];
    }
  }
#pragma unroll
  for (int i = 0; i < 8; ++i) {
    int row = bm + rowg + i;
    if (row < M) {
      float* cp = C + (size_t)row * NC + bn + colg;
      *(float4*)cp = make_float4(acc[i][0], acc[i][1], acc[i][2], acc[i][3]);
      *(float4*)(cp + 4) = make_float4(acc[i][4], acc[i][5], acc[i][6], acc[i][7]);
    }
  }
}

// ---- attention scores: a_s[n,h] = <h[n,h,:], att_src[h,:]>, same for dst ---

template <int H, int C>
__global__ void k_scores(const float* __restrict__ h, const float* __restrict__ att_s,
                         const float* __restrict__ att_d, float* __restrict__ a_s,
                         float* __restrict__ a_d, int Nn) {
  int t = blockIdx.x * blockDim.x + threadIdx.x;
  if (t >= Nn * H) return;
  int n = t / H, hh = t % H;
  const float4* hp = (const float4*)(h + (size_t)n * (H * C) + hh * C);
  const float4* sp = (const float4*)(att_s + hh * C);
  const float4* dp = (const float4*)(att_d + hh * C);
  float s = 0.f, d = 0.f;
#pragma unroll
  for (int c = 0; c < C / 4; ++c) {
    float4 v = hp[c], a = sp[c], b = dp[c];
    s += v.x * a.x + v.y * a.y + v.z * a.z + v.w * a.w;
    d += v.x * b.x + v.y * b.y + v.z * b.z + v.w * b.w;
  }
  a_s[t] = s;
  a_d[t] = d;
}

// ---- per-dst ONLINE segment softmax over CSR (thread per node) -------------

template <int H>
__global__ void k_softmax(const int* __restrict__ rowptr, const int* __restrict__ permsrc,
                          const float* __restrict__ a_s, const float* __restrict__ a_d,
                          float* __restrict__ m_out, float* __restrict__ inv_den, int Nn) {
  int n = blockIdx.x * blockDim.x + threadIdx.x;
  if (n >= Nn) return;
  int start = rowptr[n], end = rowptr[n + 1];
  float ad[H], m[H], den[H];
  if constexpr (H == 4) {
    float4 v = ((const float4*)a_d)[n];
    ad[0] = v.x; ad[1] = v.y; ad[2] = v.z; ad[3] = v.w;
  } else {
    ad[0] = a_d[n];
  }
#pragma unroll
  for (int h = 0; h < H; ++h) {
    m[h] = -INFINITY;
    den[h] = 0.f;
  }
  for (int p = start; p < end; ++p) {
    int s = permsrc[p];
    float as[H];
    if constexpr (H == 4) {
      float4 v = ((const float4*)a_s)[s];
      as[0] = v.x; as[1] = v.y; as[2] = v.z; as[3] = v.w;
    } else {
      as[0] = a_s[s];
    }
#pragma unroll
    for (int h = 0; h < H; ++h) {
      float e = as[h] + ad[h];
      e = e > 0.f ? e : SLOPE * e;
      float mn = fmaxf(m[h], e);
      den[h] = den[h] * __expf(m[h] - mn) + __expf(e - mn);
      m[h] = mn;
    }
  }
#pragma unroll
  for (int h = 0; h < H; ++h) {
    m_out[(size_t)n * H + h] = isfinite(m[h]) ? m[h] : 0.f;
    inv_den[(size_t)n * H + h] = 1.f / (den[h] + 1e-16f);
  }
}

// ---- aggregation: wave per node, lanes split HC cols, depth-2 prefetch -----
// alpha recomputed inline: alpha = exp(leaky(a_s[s]+a_d[n]) - m[n]) * inv_den[n]

template <int H, int C>
__global__ void k_aggregate(const int* __restrict__ rowptr, const int* __restrict__ permsrc,
                            const float* __restrict__ a_s, const float* __restrict__ a_d,
                            const float* __restrict__ m_arr, const float* __restrict__ inv_den,
                            const float* __restrict__ h, const float* __restrict__ bias,
                            float* __restrict__ out, int Nn) {
  constexpr int HC = H * C;
  constexpr int PL = HC / 64;  // floats per lane: 4 (HC=256) or 2 (HC=128)
  int gw = (blockIdx.x * blockDim.x + threadIdx.x) >> 6;
  if (gw >= Nn) return;
  int lane = threadIdx.x & 63;
  int col0 = lane * PL;
  int hh = col0 / C;
  int start = rowptr[gw], end = rowptr[gw + 1];
  float adv = a_d[(size_t)gw * H + hh];
  float mv = m_arr[(size_t)gw * H + hh];
  float idn = inv_den[(size_t)gw * H + hh];
  float acc[PL] = {};
  for (int c0 = start; c0 < end; c0 += 64) {
    int myp = c0 + lane;
    int sv = (myp < end) ? permsrc[myp] : 0;
    int cnt = min(64, end - c0);
    // depth-2 software pipeline: prefetch edge j+1 while FMA-ing edge j
    int s0 = __shfl(sv, 0, 64);
    float as0 = a_s[(size_t)s0 * H + hh];
    float4 v40;
    float2 v20;
    if constexpr (PL == 4) v40 = *(const float4*)(h + (size_t)s0 * HC + col0);
    else                   v20 = *(const float2*)(h + (size_t)s0 * HC + col0);
    for (int j = 0; j < cnt; ++j) {
      float as1 = 0.f;
      float4 v41;
      float2 v21;
      if (j + 1 < cnt) {
        int s1 = __shfl(sv, j + 1, 64);
        as1 = a_s[(size_t)s1 * H + hh];
        if constexpr (PL == 4) v41 = *(const float4*)(h + (size_t)s1 * HC + col0);
        else                   v21 = *(const float2*)(h + (size_t)s1 * HC + col0);
      }
      float e = as0 + adv;
      e = e > 0.f ? e : SLOPE * e;
      float alpha = __expf(e - mv) * idn;
      if constexpr (PL == 4) {
        acc[0] += alpha * v40.x;
        acc[1] += alpha * v40.y;
        acc[2] += alpha * v40.z;
        acc[3] += alpha * v40.w;
        v40 = v41;
      } else {
        acc[0] += alpha * v20.x;
        acc[1] += alpha * v20.y;
        v20 = v21;
      }
      as0 = as1;
    }
  }
#pragma unroll
  for (int j = 0; j < PL; ++j)
    out[(size_t)gw * HC + col0 + j] = acc[j] + bias[col0 + j];
}

// ---------------------------------------------------------------------------

extern "C" void kernel_launch(void* const* d_in, const int* in_sizes, int n_in,
                              void* d_out, int out_size, void* d_ws, size_t ws_size,
                              hipStream_t stream) {
  const float* x = (const float*)d_in[0];
  const int* ei = (const int*)d_in[1];
  const int Nn = in_sizes[0] / 256;
  const int E = in_sizes[1] / 2;
  const int* srcI = ei;
  const int* dstI = ei + E;

  const float* W[3]   = {(const float*)d_in[3], (const float*)d_in[7],  (const float*)d_in[11]};
  const float* ats[3] = {(const float*)d_in[4], (const float*)d_in[8],  (const float*)d_in[12]};
  const float* atd[3] = {(const float*)d_in[5], (const float*)d_in[9],  (const float*)d_in[13]};
  const float* bia[3] = {(const float*)d_in[6], (const float*)d_in[10], (const float*)d_in[14]};

  // workspace carve-up (256B aligned). Total ~110 MB.
  char* p = (char*)d_ws;
  auto alloc = [&](size_t bytes) {
    void* r = (void*)p;
    p += (bytes + 255) & ~(size_t)255;
    return r;
  };
  int* rowptr = (int*)alloc((size_t)(Nn + 1) * sizeof(int));
  int* rowcur = (int*)alloc((size_t)Nn * sizeof(int));
  int* permsrc = (int*)alloc((size_t)E * sizeof(int));
  int* ssum = (int*)alloc(1024 * sizeof(int));
  float* hbuf = (float*)alloc((size_t)Nn * 256 * sizeof(float));
  float* buf0 = (float*)alloc((size_t)Nn * 256 * sizeof(float));
  float* a_s = (float*)alloc((size_t)Nn * 4 * sizeof(float));
  float* a_d = (float*)alloc((size_t)Nn * 4 * sizeof(float));
  float* m_arr = (float*)alloc((size_t)Nn * 4 * sizeof(float));
  float* idn = (float*)alloc((size_t)Nn * 4 * sizeof(float));

  // ---- CSR build (once; reused by all layers) ----
  hipMemsetAsync(rowptr, 0, (size_t)(Nn + 1) * sizeof(int), stream);
  const int TB = 256;
  k_hist<<<(E + TB - 1) / TB, TB, 0, stream>>>(dstI, E, rowptr);
  int n1 = Nn + 1;
  int nblk = (n1 + 1023) / 1024;
  k_scan_block<<<nblk, 1024, 0, stream>>>(rowptr, n1, ssum);
  k_scan_block<<<1, 1024, 0, stream>>>(ssum, nblk, (int*)nullptr);
  k_scan_add<<<(n1 + TB - 1) / TB, TB, 0, stream>>>(rowptr, n1, ssum, rowcur, Nn);
  k_scatter<<<(E + TB - 1) / TB, TB, 0, stream>>>(srcI, dstI, E, rowcur, permsrc);

  // ---- layers ----
  // x -> buf0 -> buf0 -> d_out. (Layer1 writes back into buf0: safe, the GEMM
  // consumed it into hbuf before aggregation runs.)
  const float* xin = x;
  float* outs[3] = {buf0, buf0, (float*)d_out};
  for (int l = 0; l < 3; ++l) {
    const int H = (l == 2) ? 1 : 4;
    const int HC = (l == 2) ? 128 : 256;
    dim3 g((Nn + 127) / 128, HC / 128);
    k_gemm128<<<g, 256, 0, stream>>>(xin, W[l], hbuf, Nn, 256, HC);
    if (H == 4) {
      k_scores<4, 64><<<(Nn * 4 + TB - 1) / TB, TB, 0, stream>>>(hbuf, ats[l], atd[l], a_s, a_d, Nn);
      k_softmax<4><<<(Nn + TB - 1) / TB, TB, 0, stream>>>(rowptr, permsrc, a_s, a_d, m_arr, idn, Nn);
      k_aggregate<4, 64><<<(Nn + 3) / 4, 256, 0, stream>>>(rowptr, permsrc, a_s, a_d, m_arr, idn,
                                                           hbuf, bia[l], outs[l], Nn);
    } else {
      k_scores<1, 128><<<(Nn + TB - 1) / TB, TB, 0, stream>>>(hbuf, ats[l], atd[l], a_s, a_d, Nn);
      k_softmax<1><<<(Nn + TB - 1) / TB, TB, 0, stream>>>(rowptr, permsrc, a_s, a_d, m_arr, idn, Nn);
      k_aggregate<1, 128><<<(Nn + 3) / 4, 256, 0, stream>>>(rowptr, permsrc, a_s, a_d, m_arr, idn,
                                                            hbuf, bia[l], outs[l], Nn);
    }
    xin = outs[l];
  }
}